// Round 1
// baseline (291.558 us; speedup 1.0000x reference)
//
#include <hip/hip_runtime.h>

// MemoryBank contrastive loss, steady state.
// B=1024, D=128, C=50, K=4096, N = C*K = 204800. TEMP=0.3.
// loss = (1/B) * sum_b w_b * ( ln(sum exp(dot/T)) - dot_pos/T )
// SCALE = log2(e)/T folded into normalized bf16 features: MFMA acc feeds exp2.
//
// R6: bf16-in-LDS via register staging (was: fp32 DMA + per-wave convert).
// Old kernel was LDS-BW + VALU-pack bound: each of 4 waves read the whole
// 32 KB fp32 tile and converted it (4x redundant v_perm), 256 KB LDS reads
// per CU-tile vs 2480 cy of MFMA. Now each thread loads 64 B fp32 (2x32 B
// chunks), packs to bf16 ONCE, and ds_writes into a fragment-linear layout:
// slot S = frag(nf,ks)*64 + lane, addr = S*16. Every ds_read_b128 /
// ds_write_b128 is lane-contiguous stride-16 -> zero bank conflicts, no
// swizzle. LDS read traffic halves (16 KB/tile), pack VALU /4.
// T14 async-split: issue next tile's global loads BEFORE compute, pack+write
// AFTER (loads in flight across COMPUTE, never across a barrier).
// y=2 (512-thr blocks, 8 waves x 64 m-rows): B tile read by 2 blocks not 4
// -> L2/L3 traffic halves. Grid (640,2) = 1280 blocks = 5/CU, NITER=5.

#define XCHUNK 640
#define NITER 5            // 640 * 5 = 3200 tiles of 64 rows = 204800
#define TILE_BYTES 32768   // 64 rows x 128 fp32
#define LN2f 0.6931471805599453f
#define SCALEf 4.808983469629878f   // log2(e)/0.3

typedef __attribute__((ext_vector_type(8))) short bf16x8;
typedef __attribute__((ext_vector_type(4))) float f32x4;
typedef unsigned int u32;

__device__ __forceinline__ unsigned short f2bf(float x) {
    union { float f; unsigned int u; } c; c.f = x;
    unsigned int u = c.u;
    u = (u + 0x7fffu + ((u >> 16) & 1u)) >> 16;   // RNE (features only)
    return (unsigned short)u;
}
__device__ __forceinline__ float bf2f(unsigned short h) {
    union { unsigned int u; float f; } c; c.u = ((unsigned int)h) << 16;
    return c.f;
}
// two fp32 -> two bf16 (truncation) in one v_perm_b32: [bf(lo) | bf(hi)<<16]
__device__ __forceinline__ unsigned int pack_bf2(float lo, float hi) {
    union { float f; unsigned int u; } a, b; a.f = lo; b.f = hi;
    return __builtin_amdgcn_perm(b.u, a.u, 0x07060302u);
}

// ---- Kernel 1: normalize+scale features -> bf16; zero S and out -------------
__global__ void normalize_feat(const float* __restrict__ f,
                               unsigned short* __restrict__ featb,
                               float* __restrict__ S,
                               float* __restrict__ out) {
    const int b = blockIdx.x;          // 1024 blocks
    const int t = threadIdx.x;         // 128 threads
    if (t == 0) S[b] = 0.0f;
    if (b == 0 && t == 1) *out = 0.0f;
    float v = f[b * 128 + t];
    float ss = v * v;
    #pragma unroll
    for (int m = 1; m < 64; m <<= 1) ss += __shfl_xor(ss, m, 64);
    __shared__ float wsum[2];
    if ((t & 63) == 0) wsum[t >> 6] = ss;
    __syncthreads();
    float tot = wsum[0] + wsum[1];
    float inv = SCALEf / fmaxf(sqrtf(tot), 1e-12f);
    featb[b * 128 + t] = f2bf(v * inv);
}

// ---- Kernel 2: fused GEMM + exp2-sum ----------------------------------------
// 512 thr = 8 waves; wave owns 64 m-rows (mf=4), n-tile 64, K=128 complete.
__global__ __launch_bounds__(512, 2) void gemm_lse(
        const unsigned short* __restrict__ featb,  // [1024][128] bf16 (scaled)
        const float* __restrict__ mem,             // [204800][128] fp32
        float* __restrict__ S)                     // [1024] exp2-sums
{
    // 2 x 16 KB bf16 tiles, fragment-linear: slot (nf*4+ks)*64 + lane, 16 B each
    __shared__ uint4 ldsb[2][1024];

    const int tid  = threadIdx.x;
    const int wave = tid >> 6;        // 0..7
    const int lane = tid & 63;
    const int col  = lane & 15;
    const int quad = lane >> 4;

    const int m_wave = blockIdx.y * 512 + wave * 64;
    const int xc = blockIdx.x;        // 0..639

    // A fragments: A[m=col][k=quad*8+j], mf=4 x ks=4 (64 VGPR)
    bf16x8 afrag[4][4];
    #pragma unroll
    for (int mf = 0; mf < 4; ++mf)
        #pragma unroll
        for (int ks = 0; ks < 4; ++ks)
            afrag[mf][ks] = *(const bf16x8*)&featb[(size_t)(m_wave + mf * 16 + col) * 128
                                                   + ks * 32 + quad * 8];

    float s_part[16];
    #pragma unroll
    for (int i = 0; i < 16; ++i) s_part[i] = 0.0f;

    // Tile-invariant global byte offsets for this thread's two 32 B fp32
    // chunks. Thread t fills LDS slots {t, 512+t} (lane-linear writes); the
    // permutation lives on the GLOBAL side: slot -> (nf,ks,quad,col) ->
    // row (nf*16+col), k-bytes ks*128+quad*32.
    int o[2];
    #pragma unroll
    for (int j = 0; j < 2; ++j) {
        int Sl = j * 512 + tid;           // slot index 0..1023
        int Fi = Sl >> 6, L = Sl & 63;    // fragment id, lane within fragment
        int snf = Fi >> 2, sks = Fi & 3, sq = L >> 4, sc = L & 15;
        o[j] = (snf * 16 + sc) * 512 + sks * 128 + sq * 32;
    }

    // staged registers: 64 B fp32 in flight across COMPUTE (16 VGPR)
    float4 g0a, g0b, g1a, g1b;

    #define LOADS(t_) {                                                         \
        const char* gt = (const char*)mem + (size_t)(xc + XCHUNK * (t_)) * TILE_BYTES; \
        g0a = *(const float4*)(gt + o[0]);                                      \
        g0b = *(const float4*)(gt + o[0] + 16);                                 \
        g1a = *(const float4*)(gt + o[1]);                                      \
        g1b = *(const float4*)(gt + o[1] + 16); }

    #define PACKWRITE(bi) {                                                     \
        uint4 pk;                                                               \
        pk.x = pack_bf2(g0a.x, g0a.y); pk.y = pack_bf2(g0a.z, g0a.w);           \
        pk.z = pack_bf2(g0b.x, g0b.y); pk.w = pack_bf2(g0b.z, g0b.w);           \
        ldsb[bi][tid] = pk;                                                     \
        pk.x = pack_bf2(g1a.x, g1a.y); pk.y = pack_bf2(g1a.z, g1a.w);           \
        pk.z = pack_bf2(g1b.x, g1b.y); pk.w = pack_bf2(g1b.z, g1b.w);           \
        ldsb[bi][512 + tid] = pk; }

    #define COMPUTE(bi) {                                                       \
        _Pragma("unroll")                                                       \
        for (int nf = 0; nf < 4; ++nf) {                                        \
            f32x4 acc[4];                                                       \
            _Pragma("unroll")                                                   \
            for (int mf = 0; mf < 4; ++mf) acc[mf] = (f32x4)(0.0f);             \
            _Pragma("unroll")                                                   \
            for (int ks = 0; ks < 4; ++ks) {                                    \
                bf16x8 bfrag = *(const bf16x8*)&ldsb[bi][(nf * 4 + ks) * 64 + lane]; \
                _Pragma("unroll")                                               \
                for (int mf = 0; mf < 4; ++mf)                                  \
                    acc[mf] = __builtin_amdgcn_mfma_f32_16x16x32_bf16(          \
                        afrag[mf][ks], bfrag, acc[mf], 0, 0, 0);                \
            }                                                                   \
            _Pragma("unroll")                                                   \
            for (int mf = 0; mf < 4; ++mf)                                      \
                _Pragma("unroll")                                               \
                for (int r = 0; r < 4; ++r)                                     \
                    s_part[mf * 4 + r] += __builtin_amdgcn_exp2f(acc[mf][r]);   \
        } }

    // prologue: stage tile 0 into buf0
    LOADS(0)
    PACKWRITE(0)
    __syncthreads();

    for (int t = 0; t < NITER; ++t) {
        if (t + 1 < NITER) LOADS(t + 1)       // in flight during compute
        COMPUTE(t & 1)
        if (t + 1 < NITER) PACKWRITE((t + 1) & 1)  // other buffer; last read 2 barriers ago
        __syncthreads();
    }

    // reduce across the 16 col-lanes sharing the same quad
    #pragma unroll
    for (int d = 1; d < 16; d <<= 1)
        #pragma unroll
        for (int i = 0; i < 16; ++i)
            s_part[i] += __shfl_xor(s_part[i], d, 64);

    if (col == 0) {
        #pragma unroll
        for (int i = 0; i < 16; ++i) {
            int row = m_wave + (i >> 2) * 16 + quad * 4 + (i & 3);
            atomicAdd(&S[row], s_part[i]);
        }
    }
    #undef LOADS
    #undef PACKWRITE
    #undef COMPUTE
}

// ---- Kernel 3: pos logit + weighted mean ------------------------------------
__global__ void finalize_k(const unsigned short* __restrict__ featb,
                           const float* __restrict__ mem,
                           const int* __restrict__ labels,
                           const float* __restrict__ S,
                           float* __restrict__ out) {
    const int wave = threadIdx.x >> 6;
    const int lane = threadIdx.x & 63;
    const int b = blockIdx.x * 4 + wave;          // 256 blocks x 4 waves = 1024
    const int lab = labels[b];
    const float* mrow = mem + (size_t)lab * (4096 * 128);   // memory[lab][0][:]
    float fa = bf2f(featb[b * 128 + lane]);
    float fc = bf2f(featb[b * 128 + lane + 64]);
    float p = fa * mrow[lane] + fc * mrow[lane + 64];       // t_pos (log2 domain)
    #pragma unroll
    for (int m = 1; m < 64; m <<= 1) p += __shfl_xor(p, m, 64);
    if (lane == 0) {
        float w = (lab < 2) ? 1.3f : 1.0f;
        float v = w * LN2f * (log2f(S[b]) - p) * (1.0f / 1024.0f);
        atomicAdd(out, v);
    }
}

extern "C" void kernel_launch(void* const* d_in, const int* in_sizes, int n_in,
                              void* d_out, int out_size, void* d_ws, size_t ws_size,
                              hipStream_t stream) {
    const float* features = (const float*)d_in[0];
    const int*   labels   = (const int*)d_in[1];
    const float* memory   = (const float*)d_in[2];
    float* out = (float*)d_out;

    unsigned short* featb = (unsigned short*)d_ws;               // 256 KiB
    float* S = (float*)((char*)d_ws + 1024 * 128 * 2);           // 1024 floats

    normalize_feat<<<1024, 128, 0, stream>>>(features, featb, S, out);
    gemm_lse<<<dim3(XCHUNK, 2), 512, 0, stream>>>(featb, memory, S);
    finalize_k<<<256, 256, 0, stream>>>(featb, memory, labels, S, out);
}

// Round 2
// 207.447 us; speedup vs baseline: 1.4055x; 1.4055x over previous
//
#include <hip/hip_runtime.h>

// MemoryBank contrastive loss, steady state.
// B=1024, D=128, C=50, K=4096, N = C*K = 204800. TEMP=0.3.
// loss = (1/B) * sum_b w_b * ( ln(sum exp(dot/T)) - dot_pos/T )
// SCALE = log2(e)/T folded into normalized bf16 features: MFMA acc feeds exp2.
//
// R7: R6's bf16 fragment-linear LDS (bank conflicts 6.55M -> 0, pack-once)
// was right, but its register budget spilled: afrag(64)+staging(16)+acc(16)
// +s_part(16) ~ 120 VGPR squeezed into 72 -> scratch (WRITE_SIZE 2->10 MB),
// latency-bound collapse. Fix: halve per-wave m-ownership. 8 waves x mf=2
// (32 rows) = 256 rows/block, y=4 (R5's proven co-resident dedupe grid:
// (128,4) = 512 blocks = exactly 2/CU, NITER=25, all y-partners resident ->
// L2/L3 dedupe, FETCH ~52 MB). Pressure: afrag 32 + staging 16 + acc 8 +
// s_part 8 + bfrag/addr ~ 95 VGPR, under the 128 cap of launch_bounds(512,4)
// -> 2 blocks/CU, no spill. Per-CU phase work unchanged vs R5 (512 m-rows x
// 64 n) but LDS reads conflict-free bf16 and pack VALU /4 per CU-phase.
// T14 split: global loads for t+1 issued BEFORE COMPUTE(t), pack+ds_write
// after (loads in flight across compute, never across a barrier).

#define XCHUNK 128
#define NITER 25           // 128 * 25 = 3200 tiles of 64 rows = 204800
#define TILE_BYTES 32768   // 64 rows x 128 fp32
#define LN2f 0.6931471805599453f
#define SCALEf 4.808983469629878f   // log2(e)/0.3

typedef __attribute__((ext_vector_type(8))) short bf16x8;
typedef __attribute__((ext_vector_type(4))) float f32x4;
typedef unsigned int u32;

__device__ __forceinline__ unsigned short f2bf(float x) {
    union { float f; unsigned int u; } c; c.f = x;
    unsigned int u = c.u;
    u = (u + 0x7fffu + ((u >> 16) & 1u)) >> 16;   // RNE (features only)
    return (unsigned short)u;
}
__device__ __forceinline__ float bf2f(unsigned short h) {
    union { unsigned int u; float f; } c; c.u = ((unsigned int)h) << 16;
    return c.f;
}
// two fp32 -> two bf16 (truncation) in one v_perm_b32: [bf(lo) | bf(hi)<<16]
__device__ __forceinline__ unsigned int pack_bf2(float lo, float hi) {
    union { float f; unsigned int u; } a, b; a.f = lo; b.f = hi;
    return __builtin_amdgcn_perm(b.u, a.u, 0x07060302u);
}

// ---- Kernel 1: normalize+scale features -> bf16; zero S and out -------------
__global__ void normalize_feat(const float* __restrict__ f,
                               unsigned short* __restrict__ featb,
                               float* __restrict__ S,
                               float* __restrict__ out) {
    const int b = blockIdx.x;          // 1024 blocks
    const int t = threadIdx.x;         // 128 threads
    if (t == 0) S[b] = 0.0f;
    if (b == 0 && t == 1) *out = 0.0f;
    float v = f[b * 128 + t];
    float ss = v * v;
    #pragma unroll
    for (int m = 1; m < 64; m <<= 1) ss += __shfl_xor(ss, m, 64);
    __shared__ float wsum[2];
    if ((t & 63) == 0) wsum[t >> 6] = ss;
    __syncthreads();
    float tot = wsum[0] + wsum[1];
    float inv = SCALEf / fmaxf(sqrtf(tot), 1e-12f);
    featb[b * 128 + t] = f2bf(v * inv);
}

// ---- Kernel 2: fused GEMM + exp2-sum ----------------------------------------
// 512 thr = 8 waves; wave owns 32 m-rows (mf=2), n-tile 64, K=128 complete.
__global__ __launch_bounds__(512, 4) void gemm_lse(
        const unsigned short* __restrict__ featb,  // [1024][128] bf16 (scaled)
        const float* __restrict__ mem,             // [204800][128] fp32
        float* __restrict__ S)                     // [1024] exp2-sums
{
    // 2 x 16 KB bf16 tiles, fragment-linear: slot (nf*4+ks)*64 + lane, 16 B each
    __shared__ uint4 ldsb[2][1024];

    const int tid  = threadIdx.x;
    const int wave = tid >> 6;        // 0..7
    const int lane = tid & 63;
    const int col  = lane & 15;
    const int quad = lane >> 4;

    const int m_wave = blockIdx.y * 256 + wave * 32;
    const int xc = blockIdx.x;        // 0..127

    // A fragments: A[m=col][k=quad*8+j], mf=2 x ks=4 (32 VGPR)
    bf16x8 afrag[2][4];
    #pragma unroll
    for (int mf = 0; mf < 2; ++mf)
        #pragma unroll
        for (int ks = 0; ks < 4; ++ks)
            afrag[mf][ks] = *(const bf16x8*)&featb[(size_t)(m_wave + mf * 16 + col) * 128
                                                   + ks * 32 + quad * 8];

    float s_part[8];
    #pragma unroll
    for (int i = 0; i < 8; ++i) s_part[i] = 0.0f;

    // Tile-invariant global byte offsets for this thread's two 32 B fp32
    // chunks. Thread t fills LDS slots {t, 512+t} (lane-linear writes); the
    // permutation lives on the GLOBAL side: slot -> (nf,ks,quad,col) ->
    // row (nf*16+col), k-bytes ks*128+quad*32.
    int o[2];
    #pragma unroll
    for (int j = 0; j < 2; ++j) {
        int Sl = j * 512 + tid;           // slot index 0..1023
        int Fi = Sl >> 6, L = Sl & 63;    // fragment id, lane within fragment
        int snf = Fi >> 2, sks = Fi & 3, sq = L >> 4, sc = L & 15;
        o[j] = (snf * 16 + sc) * 512 + sks * 128 + sq * 32;
    }

    // staged registers: 64 B fp32 in flight across COMPUTE (16 VGPR)
    float4 g0a, g0b, g1a, g1b;

    #define LOADS(t_) {                                                         \
        const char* gt = (const char*)mem + (size_t)(xc + XCHUNK * (t_)) * TILE_BYTES; \
        g0a = *(const float4*)(gt + o[0]);                                      \
        g0b = *(const float4*)(gt + o[0] + 16);                                 \
        g1a = *(const float4*)(gt + o[1]);                                      \
        g1b = *(const float4*)(gt + o[1] + 16); }

    #define PACKWRITE(bi) {                                                     \
        uint4 pk;                                                               \
        pk.x = pack_bf2(g0a.x, g0a.y); pk.y = pack_bf2(g0a.z, g0a.w);           \
        pk.z = pack_bf2(g0b.x, g0b.y); pk.w = pack_bf2(g0b.z, g0b.w);           \
        ldsb[bi][tid] = pk;                                                     \
        pk.x = pack_bf2(g1a.x, g1a.y); pk.y = pack_bf2(g1a.z, g1a.w);           \
        pk.z = pack_bf2(g1b.x, g1b.y); pk.w = pack_bf2(g1b.z, g1b.w);           \
        ldsb[bi][512 + tid] = pk; }

    #define COMPUTE(bi) {                                                       \
        _Pragma("unroll")                                                       \
        for (int nf = 0; nf < 4; ++nf) {                                        \
            f32x4 acc[2];                                                       \
            _Pragma("unroll")                                                   \
            for (int mf = 0; mf < 2; ++mf) acc[mf] = (f32x4)(0.0f);             \
            _Pragma("unroll")                                                   \
            for (int ks = 0; ks < 4; ++ks) {                                    \
                bf16x8 bfrag = *(const bf16x8*)&ldsb[bi][(nf * 4 + ks) * 64 + lane]; \
                _Pragma("unroll")                                               \
                for (int mf = 0; mf < 2; ++mf)                                  \
                    acc[mf] = __builtin_amdgcn_mfma_f32_16x16x32_bf16(          \
                        afrag[mf][ks], bfrag, acc[mf], 0, 0, 0);                \
            }                                                                   \
            _Pragma("unroll")                                                   \
            for (int mf = 0; mf < 2; ++mf)                                      \
                _Pragma("unroll")                                               \
                for (int r = 0; r < 4; ++r)                                     \
                    s_part[mf * 4 + r] += __builtin_amdgcn_exp2f(acc[mf][r]);   \
        } }

    // prologue: stage tile 0 into buf0
    LOADS(0)
    PACKWRITE(0)
    __syncthreads();

    for (int t = 0; t < NITER; ++t) {
        if (t + 1 < NITER) LOADS(t + 1)       // in flight during compute
        COMPUTE(t & 1)
        if (t + 1 < NITER) PACKWRITE((t + 1) & 1)  // other buffer; last read 2 barriers ago
        __syncthreads();
    }

    // reduce across the 16 col-lanes sharing the same quad
    #pragma unroll
    for (int d = 1; d < 16; d <<= 1)
        #pragma unroll
        for (int i = 0; i < 8; ++i)
            s_part[i] += __shfl_xor(s_part[i], d, 64);

    if (col == 0) {
        #pragma unroll
        for (int i = 0; i < 8; ++i) {
            int row = m_wave + (i >> 2) * 16 + quad * 4 + (i & 3);
            atomicAdd(&S[row], s_part[i]);
        }
    }
    #undef LOADS
    #undef PACKWRITE
    #undef COMPUTE
}

// ---- Kernel 3: pos logit + weighted mean ------------------------------------
__global__ void finalize_k(const unsigned short* __restrict__ featb,
                           const float* __restrict__ mem,
                           const int* __restrict__ labels,
                           const float* __restrict__ S,
                           float* __restrict__ out) {
    const int wave = threadIdx.x >> 6;
    const int lane = threadIdx.x & 63;
    const int b = blockIdx.x * 4 + wave;          // 256 blocks x 4 waves = 1024
    const int lab = labels[b];
    const float* mrow = mem + (size_t)lab * (4096 * 128);   // memory[lab][0][:]
    float fa = bf2f(featb[b * 128 + lane]);
    float fc = bf2f(featb[b * 128 + lane + 64]);
    float p = fa * mrow[lane] + fc * mrow[lane + 64];       // t_pos (log2 domain)
    #pragma unroll
    for (int m = 1; m < 64; m <<= 1) p += __shfl_xor(p, m, 64);
    if (lane == 0) {
        float w = (lab < 2) ? 1.3f : 1.0f;
        float v = w * LN2f * (log2f(S[b]) - p) * (1.0f / 1024.0f);
        atomicAdd(out, v);
    }
}

extern "C" void kernel_launch(void* const* d_in, const int* in_sizes, int n_in,
                              void* d_out, int out_size, void* d_ws, size_t ws_size,
                              hipStream_t stream) {
    const float* features = (const float*)d_in[0];
    const int*   labels   = (const int*)d_in[1];
    const float* memory   = (const float*)d_in[2];
    float* out = (float*)d_out;

    unsigned short* featb = (unsigned short*)d_ws;               // 256 KiB
    float* S = (float*)((char*)d_ws + 1024 * 128 * 2);           // 1024 floats

    normalize_feat<<<1024, 128, 0, stream>>>(features, featb, S, out);
    gemm_lse<<<dim3(XCHUNK, 4), 512, 0, stream>>>(featb, memory, S);
    finalize_k<<<256, 256, 0, stream>>>(featb, memory, labels, S, out);
}